// Round 4
// baseline (416.336 us; speedup 1.0000x reference)
//
#include <hip/hip_runtime.h>

#define N_NODES 20000
#define N_EDGES 240000
#define IN_DIM  20
#define SH_DIM  16
#define AGG_DIM 340   // 20 sender + 320 tp
#define OUT_DIM 360   // 20 mlp + 340 aggr
#define EPS_F   1e-12f

// ---------------- edge scatter: one wave (64 lanes) per edge ----------------
__global__ __launch_bounds__(256) void edge_scatter(
    const float* __restrict__ x,
    const float* __restrict__ pos,
    const int* __restrict__ ei,
    float* __restrict__ aggr)      // [N_NODES, AGG_DIM] fp32 accumulator (ws)
{
    const int lane = threadIdx.x & 63;
    const int e    = (int)((blockIdx.x * blockDim.x + threadIdx.x) >> 6);
    if (e >= N_EDGES) return;

    const int row = ei[e];
    const int col = ei[N_EDGES + e];

    const float rx = pos[col * 3 + 0] - pos[row * 3 + 0];
    const float ry = pos[col * 3 + 1] - pos[row * 3 + 1];
    const float rz = pos[col * 3 + 2] - pos[row * 3 + 2];
    const float rinv = rsqrtf(rx * rx + ry * ry + rz * rz + EPS_F);
    const float xn = rx * rinv, yn = ry * rinv, zn = rz * rinv;

    // sender fragment: lane l < 20 holds x[row][l]
    const float s = (lane < IN_DIM) ? x[(size_t)row * IN_DIM + lane] : 0.0f;

    // For the tp features this lane touches, k = (f-20) mod 16 is constant
    // across the f += 64 loop (64 % 16 == 0). (-20 mod 16 == 12)
    const int k = (lane + 12) & 15;
    float shk;
    {
        const float x2 = xn * xn, y2 = yn * yn, z2 = zn * zn;
        switch (k) {
            case 0:  shk = 0.28209479177387814f; break;
            case 1:  shk = 0.4886025119029199f * yn; break;
            case 2:  shk = 0.4886025119029199f * zn; break;
            case 3:  shk = 0.4886025119029199f * xn; break;
            case 4:  shk = 1.0925484305920792f * xn * yn; break;
            case 5:  shk = 1.0925484305920792f * yn * zn; break;
            case 6:  shk = 0.31539156525252005f * (3.0f * z2 - 1.0f); break;
            case 7:  shk = 1.0925484305920792f * xn * zn; break;
            case 8:  shk = 0.5462742152960396f * (x2 - y2); break;
            case 9:  shk = 0.5900435899266435f * yn * (3.0f * x2 - y2); break;
            case 10: shk = 2.890611442640554f  * xn * yn * zn; break;
            case 11: shk = 0.4570457994644658f * yn * (5.0f * z2 - 1.0f); break;
            case 12: shk = 0.3731763325901154f * zn * (5.0f * z2 - 3.0f); break;
            case 13: shk = 0.4570457994644658f * xn * (5.0f * z2 - 1.0f); break;
            case 14: shk = 1.445305721320277f  * zn * (x2 - y2); break;
            default: shk = 0.5900435899266435f * xn * (x2 - 3.0f * y2); break; // k==15
        }
    }

    float* obase = aggr + (size_t)col * AGG_DIM;
#pragma unroll
    for (int i = 0; i < 6; ++i) {
        const int f = lane + 64 * i;
        if (f >= AGG_DIM) break;          // only trims iteration 5 to lanes 0..19
        const int t = f - IN_DIM;
        const int j = (t >= 0) ? (t >> 4) : 0;     // 0..19; clamp for sender lanes
        // IMPORTANT: shuffle executed unconditionally (full exec mask) —
        // a shuffle inside the divergent f<20 branch reads exec-disabled
        // source lanes => undefined data (that was the 7.25 absmax bug).
        const float tpv = __shfl(s, j, 64) * shk;
        const float val = (t >= 0) ? tpv : s;
        atomicAdd(obase + f, val);
    }
}

// ---------------- node MLP: one thread per node ----------------
__global__ __launch_bounds__(256) void node_mlp(
    const float* __restrict__ x,
    const float* __restrict__ Wpre,  const float* __restrict__ bpre,
    const float* __restrict__ Wpost, const float* __restrict__ bpost,
    const float* __restrict__ Wsc,   const float* __restrict__ bsc,
    float* __restrict__ out)
{
    __shared__ float sWpre[IN_DIM * IN_DIM];
    __shared__ float sWpost[IN_DIM * IN_DIM];
    __shared__ float sWsc[IN_DIM * IN_DIM];
    __shared__ float sb[3 * IN_DIM];

    for (int t = threadIdx.x; t < IN_DIM * IN_DIM; t += blockDim.x) {
        sWpre[t]  = Wpre[t];
        sWpost[t] = Wpost[t];
        sWsc[t]   = Wsc[t];
    }
    if (threadIdx.x < IN_DIM) {
        sb[threadIdx.x]              = bpre[threadIdx.x];
        sb[IN_DIM + threadIdx.x]     = bpost[threadIdx.x];
        sb[2 * IN_DIM + threadIdx.x] = bsc[threadIdx.x];
    }
    __syncthreads();

    const int i = (int)(blockIdx.x * blockDim.x + threadIdx.x);
    if (i >= N_NODES) return;

    float xi[IN_DIM], h[IN_DIM];
#pragma unroll
    for (int j = 0; j < IN_DIM; ++j) xi[j] = x[(size_t)i * IN_DIM + j];

#pragma unroll
    for (int j = 0; j < IN_DIM; ++j) {
        float a = sb[j];
#pragma unroll
        for (int kk = 0; kk < IN_DIM; ++kk) a = fmaf(xi[kk], sWpre[j * IN_DIM + kk], a);
        h[j] = fmaxf(a, 0.0f);
    }
#pragma unroll
    for (int j = 0; j < IN_DIM; ++j) {
        float a = sb[IN_DIM + j] + sb[2 * IN_DIM + j];
#pragma unroll
        for (int kk = 0; kk < IN_DIM; ++kk) {
            a = fmaf(h[kk],  sWpost[j * IN_DIM + kk], a);
            a = fmaf(xi[kk], sWsc[j * IN_DIM + kk],  a);
        }
        out[(size_t)i * OUT_DIM + j] = a;
    }
}

// ---------------- fp32 aggr -> out columns 20..359 (float4 copy) ----------------
__global__ __launch_bounds__(128) void aggr_to_out(
    const float* __restrict__ aggr, float* __restrict__ out)
{
    const int node = (int)blockIdx.x;
    const int q    = (int)threadIdx.x;          // 0..84 (AGG_DIM/4 = 85)
    if (q >= AGG_DIM / 4) return;
    const float4 v = ((const float4*)(aggr + (size_t)node * AGG_DIM))[q];
    ((float4*)(out + (size_t)node * OUT_DIM + IN_DIM))[q] = v;
}

extern "C" void kernel_launch(void* const* d_in, const int* in_sizes, int n_in,
                              void* d_out, int out_size, void* d_ws, size_t ws_size,
                              hipStream_t stream)
{
    const float* x     = (const float*)d_in[0];
    const float* pos   = (const float*)d_in[1];
    const int*   ei    = (const int*)d_in[2];
    const float* Wpre  = (const float*)d_in[3];
    const float* bpre  = (const float*)d_in[4];
    const float* Wpost = (const float*)d_in[5];
    const float* bpost = (const float*)d_in[6];
    const float* Wsc   = (const float*)d_in[7];
    const float* bsc   = (const float*)d_in[8];
    float* out = (float*)d_out;

    float* aggr = (float*)d_ws;
    const size_t aggr_bytes = (size_t)N_NODES * AGG_DIM * sizeof(float);

    hipMemsetAsync(aggr, 0, aggr_bytes, stream);

    // one wave per edge, 4 waves per block
    const int edge_blocks = (N_EDGES + 3) / 4;   // 60000
    edge_scatter<<<edge_blocks, 256, 0, stream>>>(x, pos, ei, aggr);

    node_mlp<<<(N_NODES + 255) / 256, 256, 0, stream>>>(
        x, Wpre, bpre, Wpost, bpost, Wsc, bsc, out);

    aggr_to_out<<<N_NODES, 128, 0, stream>>>(aggr, out);
}

// Round 5
// 174.586 us; speedup vs baseline: 2.3847x; 2.3847x over previous
//
#include <hip/hip_runtime.h>

#define N_NODES 20000
#define N_EDGES 240000
#define IN_DIM  20
#define SH_DIM  16
#define AGG_DIM 340   // 20 sender + 320 tp
#define OUT_DIM 360   // 20 mlp + 340 aggr
#define EPS_F   1e-12f
#define CAP     64    // bucket capacity per node (Binomial mean 12, max ~30)
#define OVF_MAX 8192

// SH coefficient for this lane's fixed k = (f-20) mod 16
__device__ __forceinline__ float sh_coeff(int k, float xn, float yn, float zn) {
    const float x2 = xn * xn, y2 = yn * yn, z2 = zn * zn;
    switch (k) {
        case 0:  return 0.28209479177387814f;
        case 1:  return 0.4886025119029199f * yn;
        case 2:  return 0.4886025119029199f * zn;
        case 3:  return 0.4886025119029199f * xn;
        case 4:  return 1.0925484305920792f * xn * yn;
        case 5:  return 1.0925484305920792f * yn * zn;
        case 6:  return 0.31539156525252005f * (3.0f * z2 - 1.0f);
        case 7:  return 1.0925484305920792f * xn * zn;
        case 8:  return 0.5462742152960396f * (x2 - y2);
        case 9:  return 0.5900435899266435f * yn * (3.0f * x2 - y2);
        case 10: return 2.890611442640554f  * xn * yn * zn;
        case 11: return 0.4570457994644658f * yn * (5.0f * z2 - 1.0f);
        case 12: return 0.3731763325901154f * zn * (5.0f * z2 - 3.0f);
        case 13: return 0.4570457994644658f * xn * (5.0f * z2 - 1.0f);
        case 14: return 1.445305721320277f  * zn * (x2 - y2);
        default: return 0.5900435899266435f * xn * (x2 - 3.0f * y2); // k==15
    }
}

// ---------------- bucket build: thread per edge ----------------
__global__ __launch_bounds__(256) void bucket_build(
    const int* __restrict__ ei,
    int* __restrict__ counts,      // [N_NODES]
    int* __restrict__ ovf_cnt,     // [1]
    int* __restrict__ ovf,         // [OVF_MAX]
    int* __restrict__ bucket)      // [N_NODES * CAP]
{
    const int e = (int)(blockIdx.x * blockDim.x + threadIdx.x);
    if (e >= N_EDGES) return;
    const int col  = ei[N_EDGES + e];
    const int slot = atomicAdd(&counts[col], 1);
    if (slot < CAP) {
        bucket[col * CAP + slot] = e;
    } else {
        const int o = atomicAdd(ovf_cnt, 1);
        if (o < OVF_MAX) ovf[o] = e;
    }
}

// ---------------- gather: one wave per destination node ----------------
__global__ __launch_bounds__(256) void node_gather(
    const float* __restrict__ x,
    const float* __restrict__ pos,
    const int* __restrict__ ei,
    const int* __restrict__ counts,
    const int* __restrict__ bucket,
    float* __restrict__ out)
{
    const int lane = threadIdx.x & 63;
    const int node = (int)((blockIdx.x * blockDim.x + threadIdx.x) >> 6);
    if (node >= N_NODES) return;

    int cnt = counts[node];
    if (cnt > CAP) cnt = CAP;     // overflow edges handled by overflow_scatter

    const float px = pos[node * 3 + 0];
    const float py = pos[node * 3 + 1];
    const float pz = pos[node * 3 + 2];

    const int k = (lane + 12) & 15;   // (f-20) mod 16, constant over f += 64
    float acc0 = 0.f, acc1 = 0.f, acc2 = 0.f, acc3 = 0.f, acc4 = 0.f, acc5 = 0.f;

    const int* mybucket = bucket + node * CAP;
    for (int i = 0; i < cnt; ++i) {
        const int eid = mybucket[i];
        const int row = ei[eid];

        const float rx = px - pos[row * 3 + 0];
        const float ry = py - pos[row * 3 + 1];
        const float rz = pz - pos[row * 3 + 2];
        const float rinv = rsqrtf(rx * rx + ry * ry + rz * rz + EPS_F);
        const float shk  = sh_coeff(k, rx * rinv, ry * rinv, rz * rinv);

        const float s = (lane < IN_DIM) ? x[(size_t)row * IN_DIM + lane] : 0.0f;

        // slot ii covers feature f = lane + 64*ii; tp source j = (f-20)>>4.
        // All shuffles full-exec (no divergence in this loop).
        {   // ii=0: f=lane; lanes<20 are sender, rest tp (j = (lane-20)>>4 for lane>=20)
            const int t = lane - IN_DIM;
            const float tpv = __shfl(s, (t >= 0) ? (t >> 4) : 0, 64) * shk;
            acc0 += (t >= 0) ? tpv : s;
        }
        acc1 += __shfl(s, (lane + 44)  >> 4, 64) * shk;   // f=lane+64
        acc2 += __shfl(s, (lane + 108) >> 4, 64) * shk;   // f=lane+128
        acc3 += __shfl(s, (lane + 172) >> 4, 64) * shk;   // f=lane+192
        acc4 += __shfl(s, (lane + 236) >> 4, 64) * shk;   // f=lane+256
        acc5 += __shfl(s, (lane + 300) >> 4, 64) * shk;   // f=lane+320 (lanes<20 valid)
    }

    float* obase = out + (size_t)node * OUT_DIM + IN_DIM;   // aggr block, cols 20..359
    obase[lane]       = acc0;
    obase[lane + 64]  = acc1;
    obase[lane + 128] = acc2;
    obase[lane + 192] = acc3;
    obase[lane + 256] = acc4;
    if (lane < IN_DIM) obase[lane + 320] = acc5;
}

// ---------------- overflow edges (normally zero): atomics into out ----------------
__global__ __launch_bounds__(256) void overflow_scatter(
    const float* __restrict__ x,
    const float* __restrict__ pos,
    const int* __restrict__ ei,
    const int* __restrict__ ovf_cnt,
    const int* __restrict__ ovf,
    float* __restrict__ out)
{
    const int lane = threadIdx.x & 63;
    const int wid  = threadIdx.x >> 6;       // 0..3, single block
    int n = ovf_cnt[0];
    if (n > OVF_MAX) n = OVF_MAX;

    for (int idx = wid; idx < n; idx += 4) {
        const int e   = ovf[idx];
        const int row = ei[e];
        const int col = ei[N_EDGES + e];

        const float rx = pos[col * 3 + 0] - pos[row * 3 + 0];
        const float ry = pos[col * 3 + 1] - pos[row * 3 + 1];
        const float rz = pos[col * 3 + 2] - pos[row * 3 + 2];
        const float rinv = rsqrtf(rx * rx + ry * ry + rz * rz + EPS_F);
        const float shk  = sh_coeff((lane + 12) & 15, rx * rinv, ry * rinv, rz * rinv);

        const float s = (lane < IN_DIM) ? x[(size_t)row * IN_DIM + lane] : 0.0f;
        float* obase = out + (size_t)col * OUT_DIM + IN_DIM;

#pragma unroll
        for (int ii = 0; ii < 6; ++ii) {
            const int f = lane + 64 * ii;
            const int t = f - IN_DIM;
            const float tpv = __shfl(s, (t >= 0) ? (t >> 4) : 0, 64) * shk;  // full exec
            const float val = (t >= 0) ? tpv : s;
            if (f < AGG_DIM) atomicAdd(obase + f, val);
        }
    }
}

// ---------------- node MLP: one thread per node ----------------
__global__ __launch_bounds__(256) void node_mlp(
    const float* __restrict__ x,
    const float* __restrict__ Wpre,  const float* __restrict__ bpre,
    const float* __restrict__ Wpost, const float* __restrict__ bpost,
    const float* __restrict__ Wsc,   const float* __restrict__ bsc,
    float* __restrict__ out)
{
    __shared__ float sWpre[IN_DIM * IN_DIM];
    __shared__ float sWpost[IN_DIM * IN_DIM];
    __shared__ float sWsc[IN_DIM * IN_DIM];
    __shared__ float sb[3 * IN_DIM];

    for (int t = threadIdx.x; t < IN_DIM * IN_DIM; t += blockDim.x) {
        sWpre[t]  = Wpre[t];
        sWpost[t] = Wpost[t];
        sWsc[t]   = Wsc[t];
    }
    if (threadIdx.x < IN_DIM) {
        sb[threadIdx.x]              = bpre[threadIdx.x];
        sb[IN_DIM + threadIdx.x]     = bpost[threadIdx.x];
        sb[2 * IN_DIM + threadIdx.x] = bsc[threadIdx.x];
    }
    __syncthreads();

    const int i = (int)(blockIdx.x * blockDim.x + threadIdx.x);
    if (i >= N_NODES) return;

    float xi[IN_DIM], h[IN_DIM];
#pragma unroll
    for (int j = 0; j < IN_DIM; ++j) xi[j] = x[(size_t)i * IN_DIM + j];

#pragma unroll
    for (int j = 0; j < IN_DIM; ++j) {
        float a = sb[j];
#pragma unroll
        for (int kk = 0; kk < IN_DIM; ++kk) a = fmaf(xi[kk], sWpre[j * IN_DIM + kk], a);
        h[j] = fmaxf(a, 0.0f);
    }
#pragma unroll
    for (int j = 0; j < IN_DIM; ++j) {
        float a = sb[IN_DIM + j] + sb[2 * IN_DIM + j];
#pragma unroll
        for (int kk = 0; kk < IN_DIM; ++kk) {
            a = fmaf(h[kk],  sWpost[j * IN_DIM + kk], a);
            a = fmaf(xi[kk], sWsc[j * IN_DIM + kk],  a);
        }
        out[(size_t)i * OUT_DIM + j] = a;
    }
}

extern "C" void kernel_launch(void* const* d_in, const int* in_sizes, int n_in,
                              void* d_out, int out_size, void* d_ws, size_t ws_size,
                              hipStream_t stream)
{
    const float* x     = (const float*)d_in[0];
    const float* pos   = (const float*)d_in[1];
    const int*   ei    = (const int*)d_in[2];
    const float* Wpre  = (const float*)d_in[3];
    const float* bpre  = (const float*)d_in[4];
    const float* Wpost = (const float*)d_in[5];
    const float* bpost = (const float*)d_in[6];
    const float* Wsc   = (const float*)d_in[7];
    const float* bsc   = (const float*)d_in[8];
    float* out = (float*)d_out;

    // ws layout (ints): [counts 20000][ovf_cnt 1][ovf 8192][bucket 20000*64]
    int* ws_i    = (int*)d_ws;
    int* counts  = ws_i;
    int* ovf_cnt = ws_i + N_NODES;
    int* ovf     = ws_i + N_NODES + 1;
    int* bucket  = ws_i + N_NODES + 1 + OVF_MAX;

    hipMemsetAsync(counts, 0, (size_t)(N_NODES + 1) * sizeof(int), stream); // counts + ovf_cnt

    bucket_build<<<(N_EDGES + 255) / 256, 256, 0, stream>>>(ei, counts, ovf_cnt, ovf, bucket);

    node_gather<<<(N_NODES * 64 + 255) / 256, 256, 0, stream>>>(x, pos, ei, counts, bucket, out);

    node_mlp<<<(N_NODES + 255) / 256, 256, 0, stream>>>(
        x, Wpre, bpre, Wpost, bpost, Wsc, bsc, out);

    // must run after node_gather (adds on top of stored aggr)
    overflow_scatter<<<1, 256, 0, stream>>>(x, pos, ei, ovf_cnt, ovf, out);
}

// Round 6
// 134.715 us; speedup vs baseline: 3.0905x; 1.2960x over previous
//
#include <hip/hip_runtime.h>

#define N_NODES 20000
#define N_EDGES 240000
#define IN_DIM  20
#define SH_DIM  16
#define AGG_DIM 340   // 20 sender + 320 tp
#define OUT_DIM 360   // 20 mlp + 340 aggr
#define EPS_F   1e-12f
#define CAP     64    // bucket capacity per node (Binomial mean 12, max ~35)
#define OVF_MAX 8192
#define MLP_BLOCKS ((N_NODES + 255) / 256)   // 79

// ---- SH as A*m1 + B*m2, m = product of 3 factors from {1,x,y,z} ----
// factor code 2b: 0->1, 1->x, 2->y, 3->z ; packed f1 | f2<<2 | f3<<4
__device__ const float SH_A[16] = {
    0.28209479177387814f, 0.4886025119029199f, 0.4886025119029199f, 0.4886025119029199f,
    1.0925484305920792f,  1.0925484305920792f, 0.94617469575756015f, 1.0925484305920792f,
    0.5462742152960396f,  1.7701307697799305f, 2.890611442640554f,   2.285228997322329f,
    1.865881662950577f,   2.285228997322329f,  1.445305721320277f,   0.5900435899266435f };
__device__ const float SH_B[16] = {
    0.f, 0.f, 0.f, 0.f,
    0.f, 0.f, -0.31539156525252005f, 0.f,
    -0.5462742152960396f, -0.5900435899266435f, 0.f, -0.4570457994644658f,
    -1.1195289977703462f, -0.4570457994644658f, -1.445305721320277f, -1.7701307697799305f };
__device__ const int SH_M1[16] = { 0, 2, 3, 1, 9, 14, 15, 13, 5, 37, 57, 62, 63, 61, 53, 21 };
__device__ const int SH_M2[16] = { 0, 0, 0, 0, 0, 0,  0,  0, 10, 42, 0,  2,  3,  1,  58, 26 };

__device__ __forceinline__ float pick(int c, float xn, float yn, float zn) {
    const float ab = (c & 1) ? xn : 1.0f;
    const float cd = (c & 1) ? zn : yn;
    return (c & 2) ? cd : ab;
}

// switch version, used only in the (normally empty) overflow path
__device__ __forceinline__ float sh_coeff(int k, float xn, float yn, float zn) {
    const float x2 = xn * xn, y2 = yn * yn, z2 = zn * zn;
    switch (k) {
        case 0:  return 0.28209479177387814f;
        case 1:  return 0.4886025119029199f * yn;
        case 2:  return 0.4886025119029199f * zn;
        case 3:  return 0.4886025119029199f * xn;
        case 4:  return 1.0925484305920792f * xn * yn;
        case 5:  return 1.0925484305920792f * yn * zn;
        case 6:  return 0.31539156525252005f * (3.0f * z2 - 1.0f);
        case 7:  return 1.0925484305920792f * xn * zn;
        case 8:  return 0.5462742152960396f * (x2 - y2);
        case 9:  return 0.5900435899266435f * yn * (3.0f * x2 - y2);
        case 10: return 2.890611442640554f  * xn * yn * zn;
        case 11: return 0.4570457994644658f * yn * (5.0f * z2 - 1.0f);
        case 12: return 0.3731763325901154f * zn * (5.0f * z2 - 3.0f);
        case 13: return 0.4570457994644658f * xn * (5.0f * z2 - 1.0f);
        case 14: return 1.445305721320277f  * zn * (x2 - y2);
        default: return 0.5900435899266435f * xn * (x2 - 3.0f * y2); // k==15
    }
}

// ---------------- bucket build (stores ROW) + pos4 staging ----------------
__global__ __launch_bounds__(256) void bucket_build(
    const float* __restrict__ pos,
    const int* __restrict__ ei,
    float4* __restrict__ pos4,     // [N_NODES]
    int* __restrict__ counts,      // [N_NODES]
    int* __restrict__ ovf_cnt,     // [1]
    int* __restrict__ ovf,         // [OVF_MAX]
    int* __restrict__ bucket)      // [N_NODES * CAP] holds ROW per slot
{
    const int t = (int)(blockIdx.x * blockDim.x + threadIdx.x);
    if (t < N_EDGES) {
        const int col  = ei[N_EDGES + t];
        const int slot = atomicAdd(&counts[col], 1);
        if (slot < CAP) {
            bucket[col * CAP + slot] = ei[t];   // store row directly
        } else {
            const int o = atomicAdd(ovf_cnt, 1);
            if (o < OVF_MAX) ovf[o] = t;
        }
    } else {
        const int n = t - N_EDGES;
        if (n < N_NODES)
            pos4[n] = make_float4(pos[n * 3 + 0], pos[n * 3 + 1], pos[n * 3 + 2], 0.0f);
    }
}

// ---------------- gather: one wave per destination node ----------------
__global__ __launch_bounds__(256) void node_gather(
    const float* __restrict__ x,
    const float4* __restrict__ pos4,
    const int* __restrict__ counts,
    const int* __restrict__ bucket,
    float* __restrict__ out)
{
    const int lane = threadIdx.x & 63;
    const int node = (int)((blockIdx.x * blockDim.x + threadIdx.x) >> 6);
    if (node >= N_NODES) return;

    int cnt = counts[node];
    if (cnt > CAP) cnt = CAP;     // overflow edges handled in node_mlp's extra block

    const float4 p = pos4[node];

    // per-lane loop-invariant SH decomposition
    const int   k  = (lane + 12) & 15;   // (f-20) mod 16, constant over f += 64
    const float A  = SH_A[k], B = SH_B[k];
    const int   c1 = SH_M1[k], c2 = SH_M2[k];

    float acc0 = 0.f, acc1 = 0.f, acc2 = 0.f, acc3 = 0.f, acc4 = 0.f, acc5 = 0.f;

    if (cnt > 0) {
        // coalesced pre-load of this wave's bucket into one register per lane
        const int* mybucket = bucket + node * CAP;
        const int rload = mybucket[min(lane, cnt - 1)];

        for (int i = 0; i < cnt; ++i) {
            const int row = __shfl(rload, i, 64);

            const float4 q = pos4[row];
            const float rx = p.x - q.x, ry = p.y - q.y, rz = p.z - q.z;
            const float rinv = rsqrtf(rx * rx + ry * ry + rz * rz + EPS_F);
            const float xn = rx * rinv, yn = ry * rinv, zn = rz * rinv;

            // branch-free SH for this lane's k
            const float m1 = pick(c1, xn, yn, zn) * pick(c1 >> 2, xn, yn, zn) * pick(c1 >> 4, xn, yn, zn);
            const float m2 = pick(c2, xn, yn, zn) * pick(c2 >> 2, xn, yn, zn) * pick(c2 >> 4, xn, yn, zn);
            const float shk = fmaf(B, m2, A * m1);

            // sender fragment (clamped address; lanes >=20 hold junk never used:
            // shuffles only source lanes 0..19, direct use only lanes <20)
            const float s = x[(size_t)row * IN_DIM + min(lane, IN_DIM - 1)];

            {   // f = lane: sender for lanes<20, tp otherwise
                const int t = lane - IN_DIM;
                const float tpv = __shfl(s, (t >= 0) ? (t >> 4) : 0, 64) * shk;
                acc0 += (t >= 0) ? tpv : s;
            }
            acc1 += __shfl(s, (lane + 44)  >> 4, 64) * shk;   // f=lane+64
            acc2 += __shfl(s, (lane + 108) >> 4, 64) * shk;   // f=lane+128
            acc3 += __shfl(s, (lane + 172) >> 4, 64) * shk;   // f=lane+192
            acc4 += __shfl(s, (lane + 236) >> 4, 64) * shk;   // f=lane+256
            acc5 += __shfl(s, (lane + 300) >> 4, 64) * shk;   // f=lane+320 (lanes<20 valid)
        }
    }

    float* obase = out + (size_t)node * OUT_DIM + IN_DIM;   // aggr block, cols 20..359
    obase[lane]       = acc0;
    obase[lane + 64]  = acc1;
    obase[lane + 128] = acc2;
    obase[lane + 192] = acc3;
    obase[lane + 256] = acc4;
    if (lane < IN_DIM) obase[lane + 320] = acc5;
}

// ---------------- node MLP (blocks 0..MLP_BLOCKS-1) + overflow (last block) ----------------
__global__ __launch_bounds__(256) void node_mlp(
    const float* __restrict__ x,
    const float* __restrict__ pos,
    const int* __restrict__ ei,
    const int* __restrict__ ovf_cnt,
    const int* __restrict__ ovf,
    const float* __restrict__ Wpre,  const float* __restrict__ bpre,
    const float* __restrict__ Wpost, const float* __restrict__ bpost,
    const float* __restrict__ Wsc,   const float* __restrict__ bsc,
    float* __restrict__ out)
{
    if ((int)blockIdx.x >= MLP_BLOCKS) {
        // ---- overflow edges (normally zero): atomics on top of gathered sums ----
        const int lane = threadIdx.x & 63;
        const int wid  = threadIdx.x >> 6;
        int n = ovf_cnt[0];
        if (n > OVF_MAX) n = OVF_MAX;
        for (int idx = wid; idx < n; idx += 4) {
            const int e   = ovf[idx];
            const int row = ei[e];
            const int col = ei[N_EDGES + e];
            const float rx = pos[col * 3 + 0] - pos[row * 3 + 0];
            const float ry = pos[col * 3 + 1] - pos[row * 3 + 1];
            const float rz = pos[col * 3 + 2] - pos[row * 3 + 2];
            const float rinv = rsqrtf(rx * rx + ry * ry + rz * rz + EPS_F);
            const float shk  = sh_coeff((lane + 12) & 15, rx * rinv, ry * rinv, rz * rinv);
            const float s = x[(size_t)row * IN_DIM + min(lane, IN_DIM - 1)];
            float* obase = out + (size_t)col * OUT_DIM + IN_DIM;
#pragma unroll
            for (int ii = 0; ii < 6; ++ii) {
                const int f = lane + 64 * ii;
                const int t = f - IN_DIM;
                const float tpv = __shfl(s, (t >= 0) ? (t >> 4) : 0, 64) * shk;  // full exec
                const float val = (t >= 0) ? tpv : s;
                if (f < AGG_DIM) atomicAdd(obase + f, val);
            }
        }
        return;
    }

    __shared__ float sWpre[IN_DIM * IN_DIM];
    __shared__ float sWpost[IN_DIM * IN_DIM];
    __shared__ float sWsc[IN_DIM * IN_DIM];
    __shared__ float sb[3 * IN_DIM];

    for (int t = threadIdx.x; t < IN_DIM * IN_DIM; t += blockDim.x) {
        sWpre[t]  = Wpre[t];
        sWpost[t] = Wpost[t];
        sWsc[t]   = Wsc[t];
    }
    if (threadIdx.x < IN_DIM) {
        sb[threadIdx.x]              = bpre[threadIdx.x];
        sb[IN_DIM + threadIdx.x]     = bpost[threadIdx.x];
        sb[2 * IN_DIM + threadIdx.x] = bsc[threadIdx.x];
    }
    __syncthreads();

    const int i = (int)(blockIdx.x * blockDim.x + threadIdx.x);
    if (i >= N_NODES) return;

    float xi[IN_DIM], h[IN_DIM];
#pragma unroll
    for (int j = 0; j < IN_DIM; ++j) xi[j] = x[(size_t)i * IN_DIM + j];

#pragma unroll
    for (int j = 0; j < IN_DIM; ++j) {
        float a = sb[j];
#pragma unroll
        for (int kk = 0; kk < IN_DIM; ++kk) a = fmaf(xi[kk], sWpre[j * IN_DIM + kk], a);
        h[j] = fmaxf(a, 0.0f);
    }
#pragma unroll
    for (int j = 0; j < IN_DIM; ++j) {
        float a = sb[IN_DIM + j] + sb[2 * IN_DIM + j];
#pragma unroll
        for (int kk = 0; kk < IN_DIM; ++kk) {
            a = fmaf(h[kk],  sWpost[j * IN_DIM + kk], a);
            a = fmaf(xi[kk], sWsc[j * IN_DIM + kk],  a);
        }
        out[(size_t)i * OUT_DIM + j] = a;
    }
}

extern "C" void kernel_launch(void* const* d_in, const int* in_sizes, int n_in,
                              void* d_out, int out_size, void* d_ws, size_t ws_size,
                              hipStream_t stream)
{
    const float* x     = (const float*)d_in[0];
    const float* pos   = (const float*)d_in[1];
    const int*   ei    = (const int*)d_in[2];
    const float* Wpre  = (const float*)d_in[3];
    const float* bpre  = (const float*)d_in[4];
    const float* Wpost = (const float*)d_in[5];
    const float* bpost = (const float*)d_in[6];
    const float* Wsc   = (const float*)d_in[7];
    const float* bsc   = (const float*)d_in[8];
    float* out = (float*)d_out;

    // ws layout: [pos4: N_NODES float4][counts: N][ovf_cnt: 1][ovf: OVF_MAX][bucket: N*CAP]
    float4* pos4 = (float4*)d_ws;
    int* ws_i    = (int*)(pos4 + N_NODES);
    int* counts  = ws_i;
    int* ovf_cnt = ws_i + N_NODES;
    int* ovf     = ws_i + N_NODES + 1;
    int* bucket  = ws_i + N_NODES + 1 + OVF_MAX;

    hipMemsetAsync(counts, 0, (size_t)(N_NODES + 1) * sizeof(int), stream); // counts + ovf_cnt

    const int bb_threads = N_EDGES + N_NODES;
    bucket_build<<<(bb_threads + 255) / 256, 256, 0, stream>>>(
        pos, ei, pos4, counts, ovf_cnt, ovf, bucket);

    node_gather<<<(N_NODES * 64 + 255) / 256, 256, 0, stream>>>(
        x, pos4, counts, bucket, out);

    // mlp blocks + 1 overflow block (runs after node_gather; atomics are safe)
    node_mlp<<<MLP_BLOCKS + 1, 256, 0, stream>>>(
        x, pos, ei, ovf_cnt, ovf, Wpre, bpre, Wpost, bpost, Wsc, bsc, out);
}

// Round 7
// 132.449 us; speedup vs baseline: 3.1434x; 1.0171x over previous
//
#include <hip/hip_runtime.h>

#define N_NODES 20000
#define N_EDGES 240000
#define IN_DIM  20
#define AGG_DIM 340   // 20 sender + 320 tp
#define OUT_DIM 360   // 20 mlp + 340 aggr
#define EPS_F   1e-12f
#define CAP     64    // bucket capacity per node (Binomial mean 12, max ~35)
#define WPAD    21    // LDS leading-dim pad for conflict-free W rows

// ---- SH as A*m1 + B*m2, m = product of 3 factors from {1,x,y,z} ----
// factor code 2b: 0->1, 1->x, 2->y, 3->z ; packed f1 | f2<<2 | f3<<4
__device__ const float SH_A[16] = {
    0.28209479177387814f, 0.4886025119029199f, 0.4886025119029199f, 0.4886025119029199f,
    1.0925484305920792f,  1.0925484305920792f, 0.94617469575756015f, 1.0925484305920792f,
    0.5462742152960396f,  1.7701307697799305f, 2.890611442640554f,   2.285228997322329f,
    1.865881662950577f,   2.285228997322329f,  1.445305721320277f,   0.5900435899266435f };
__device__ const float SH_B[16] = {
    0.f, 0.f, 0.f, 0.f,
    0.f, 0.f, -0.31539156525252005f, 0.f,
    -0.5462742152960396f, -0.5900435899266435f, 0.f, -0.4570457994644658f,
    -1.1195289977703462f, -0.4570457994644658f, -1.445305721320277f, -1.7701307697799305f };
__device__ const int SH_M1[16] = { 0, 2, 3, 1, 9, 14, 15, 13, 5, 37, 57, 62, 63, 61, 53, 21 };
__device__ const int SH_M2[16] = { 0, 0, 0, 0, 0, 0,  0,  0, 10, 42, 0,  2,  3,  1,  58, 26 };

__device__ __forceinline__ float pick(int c, float xn, float yn, float zn) {
    const float ab = (c & 1) ? xn : 1.0f;
    const float cd = (c & 1) ? zn : yn;
    return (c & 2) ? cd : ab;
}

// one edge's contribution (full-exec; call only with all 64 lanes active)
__device__ __forceinline__ void edge_accum(
    const float4 p, const float4 q, const float sc,
    float A, float B, int c1, int c2,
    int lane, int j0, int j1, int j2, int j3, int j4, int j5,
    float& acc0, float& acc1, float& acc2, float& acc3, float& acc4, float& acc5)
{
    const float rx = p.x - q.x, ry = p.y - q.y, rz = p.z - q.z;
    const float rinv = rsqrtf(rx * rx + ry * ry + rz * rz + EPS_F);
    const float xn = rx * rinv, yn = ry * rinv, zn = rz * rinv;

    const float m1 = pick(c1, xn, yn, zn) * pick(c1 >> 2, xn, yn, zn) * pick(c1 >> 4, xn, yn, zn);
    const float m2 = pick(c2, xn, yn, zn) * pick(c2 >> 2, xn, yn, zn) * pick(c2 >> 4, xn, yn, zn);
    const float shk = fmaf(B, m2, A * m1);

    const float t0 = __shfl(sc, j0, 64) * shk;
    acc0 += (lane >= IN_DIM) ? t0 : sc;
    acc1 = fmaf(__shfl(sc, j1, 64), shk, acc1);
    acc2 = fmaf(__shfl(sc, j2, 64), shk, acc2);
    acc3 = fmaf(__shfl(sc, j3, 64), shk, acc3);
    acc4 = fmaf(__shfl(sc, j4, 64), shk, acc4);
    acc5 = fmaf(__shfl(sc, j5, 64), shk, acc5);
}

// ---------------- bucket build (stores ROW per slot) + pos4 staging ----------------
__global__ __launch_bounds__(256) void bucket_build(
    const float* __restrict__ pos,
    const int* __restrict__ ei,
    float4* __restrict__ pos4,     // [N_NODES]
    int* __restrict__ counts,      // [N_NODES]
    int* __restrict__ ovf_cnt,     // [1]
    int* __restrict__ ovf,         // [N_EDGES] (exact: never loses an edge)
    int* __restrict__ bucket)      // [N_NODES * CAP]
{
    const int t = (int)(blockIdx.x * blockDim.x + threadIdx.x);
    if (t < N_EDGES) {
        const int col  = ei[N_EDGES + t];
        const int slot = atomicAdd(&counts[col], 1);
        if (slot < CAP) {
            bucket[col * CAP + slot] = ei[t];   // store row directly
        } else {
            const int o = atomicAdd(ovf_cnt, 1);
            ovf[o] = t;                          // o < N_EDGES always
        }
    } else {
        const int n = t - N_EDGES;
        if (n < N_NODES)
            pos4[n] = make_float4(pos[n * 3 + 0], pos[n * 3 + 1], pos[n * 3 + 2], 0.0f);
    }
}

// ---------------- fused gather + MLP: one wave per destination node ----------------
__global__ __launch_bounds__(256) void gather_mlp(
    const float* __restrict__ x,
    const float4* __restrict__ pos4,
    const int* __restrict__ ei,
    const int* __restrict__ counts,
    const int* __restrict__ bucket,
    const int* __restrict__ ovf_cnt,
    const int* __restrict__ ovf,
    const float* __restrict__ Wpre,  const float* __restrict__ bpre,
    const float* __restrict__ Wpost, const float* __restrict__ bpost,
    const float* __restrict__ Wsc,   const float* __restrict__ bsc,
    float* __restrict__ out)
{
    __shared__ float sWpre[IN_DIM * WPAD];
    __shared__ float sWpost[IN_DIM * WPAD];
    __shared__ float sWsc[IN_DIM * WPAD];
    __shared__ float sB[3 * IN_DIM];

    for (int t = threadIdx.x; t < IN_DIM * IN_DIM; t += 256) {
        const int r = t / IN_DIM, c = t - r * IN_DIM;
        sWpre[r * WPAD + c]  = Wpre[t];
        sWpost[r * WPAD + c] = Wpost[t];
        sWsc[r * WPAD + c]   = Wsc[t];
    }
    if (threadIdx.x < IN_DIM) {
        sB[threadIdx.x]              = bpre[threadIdx.x];
        sB[IN_DIM + threadIdx.x]     = bpost[threadIdx.x];
        sB[2 * IN_DIM + threadIdx.x] = bsc[threadIdx.x];
    }
    __syncthreads();

    const int lane   = threadIdx.x & 63;
    const int node   = (int)((blockIdx.x * blockDim.x + threadIdx.x) >> 6); // grid exact
    const int lane20 = min(lane, IN_DIM - 1);

    // per-lane loop-invariant SH decomposition + shuffle sources
    const int   k  = (lane + 12) & 15;   // (f-20) mod 16, constant over f += 64
    const float A  = SH_A[k], B = SH_B[k];
    const int   c1 = SH_M1[k], c2 = SH_M2[k];
    const int j0 = (lane >= IN_DIM) ? ((lane - IN_DIM) >> 4) : 0;
    const int j1 = (lane + 44)  >> 4;
    const int j2 = (lane + 108) >> 4;
    const int j3 = (lane + 172) >> 4;
    const int j4 = (lane + 236) >> 4;
    const int j5 = (lane + 300) >> 4;

    const float4 p = pos4[node];
    const int cnt_raw = counts[node];
    const int cnt = min(cnt_raw, CAP);

    // MLP input prefetch (independent of gather loop)
    const float xi = x[(size_t)node * IN_DIM + lane20];

    float acc0 = 0.f, acc1 = 0.f, acc2 = 0.f, acc3 = 0.f, acc4 = 0.f, acc5 = 0.f;

    if (cnt > 0) {
        // coalesced pre-load of this wave's bucket into one register per lane
        const int rl = bucket[node * CAP + min(lane, cnt - 1)];
        int row0 = __shfl(rl, 0, 64);
        float4 q = pos4[row0];
        float  s = x[(size_t)row0 * IN_DIM + lane20];

        for (int i = 0; i < cnt; ++i) {
            const float4 qc = q;
            const float  sc = s;
            if (i + 1 < cnt) {              // wave-uniform; 1-edge lookahead
                const int rn = __shfl(rl, i + 1, 64);
                q = pos4[rn];
                s = x[(size_t)rn * IN_DIM + lane20];
            }
            edge_accum(p, qc, sc, A, B, c1, c2, lane, j0, j1, j2, j3, j4, j5,
                       acc0, acc1, acc2, acc3, acc4, acc5);
        }
    }

    // overflow (cnt_raw > CAP is statistically unreachable for random graphs,
    // but exact for any input): this node's wave scans the global overflow list.
    if (cnt_raw > CAP) {
        const int m = *ovf_cnt;
        for (int i = 0; i < m; ++i) {
            const int e = ovf[i];
            if (ei[N_EDGES + e] != node) continue;   // wave-uniform
            const int row = ei[e];
            const float4 qc = pos4[row];
            const float  sc = x[(size_t)row * IN_DIM + lane20];
            edge_accum(p, qc, sc, A, B, c1, c2, lane, j0, j1, j2, j3, j4, j5,
                       acc0, acc1, acc2, acc3, acc4, acc5);
        }
    }

    float* obase = out + (size_t)node * OUT_DIM + IN_DIM;   // aggr block, cols 20..359
    obase[lane]       = acc0;
    obase[lane + 64]  = acc1;
    obase[lane + 128] = acc2;
    obase[lane + 192] = acc3;
    obase[lane + 256] = acc4;
    if (lane < IN_DIM) obase[lane + 320] = acc5;

    // ---- fused node MLP (lane j < 20 computes output feature j) ----
    float h = sB[lane20];
#pragma unroll
    for (int kk = 0; kk < IN_DIM; ++kk)
        h = fmaf(__shfl(xi, kk, 64), sWpre[lane20 * WPAD + kk], h);
    h = fmaxf(h, 0.0f);

    float o = sB[IN_DIM + lane20] + sB[2 * IN_DIM + lane20];
#pragma unroll
    for (int kk = 0; kk < IN_DIM; ++kk) {
        o = fmaf(__shfl(h,  kk, 64), sWpost[lane20 * WPAD + kk], o);
        o = fmaf(__shfl(xi, kk, 64), sWsc[lane20 * WPAD + kk],  o);
    }
    if (lane < IN_DIM) out[(size_t)node * OUT_DIM + lane] = o;
}

extern "C" void kernel_launch(void* const* d_in, const int* in_sizes, int n_in,
                              void* d_out, int out_size, void* d_ws, size_t ws_size,
                              hipStream_t stream)
{
    const float* x     = (const float*)d_in[0];
    const float* pos   = (const float*)d_in[1];
    const int*   ei    = (const int*)d_in[2];
    const float* Wpre  = (const float*)d_in[3];
    const float* bpre  = (const float*)d_in[4];
    const float* Wpost = (const float*)d_in[5];
    const float* bpost = (const float*)d_in[6];
    const float* Wsc   = (const float*)d_in[7];
    const float* bsc   = (const float*)d_in[8];
    float* out = (float*)d_out;

    // ws layout: [pos4: N float4][counts: N][ovf_cnt: 1][ovf: N_EDGES][bucket: N*CAP]
    float4* pos4 = (float4*)d_ws;
    int* ws_i    = (int*)(pos4 + N_NODES);
    int* counts  = ws_i;
    int* ovf_cnt = ws_i + N_NODES;
    int* ovf     = ws_i + N_NODES + 1;
    int* bucket  = ws_i + N_NODES + 1 + N_EDGES;

    hipMemsetAsync(counts, 0, (size_t)(N_NODES + 1) * sizeof(int), stream); // counts + ovf_cnt

    const int bb_threads = N_EDGES + N_NODES;
    bucket_build<<<(bb_threads + 255) / 256, 256, 0, stream>>>(
        pos, ei, pos4, counts, ovf_cnt, ovf, bucket);

    gather_mlp<<<(N_NODES * 64) / 256, 256, 0, stream>>>(   // exactly 5000 blocks
        x, pos4, ei, counts, bucket, ovf_cnt, ovf,
        Wpre, bpre, Wpost, bpost, Wsc, bsc, out);
}